// Round 4
// baseline (91.130 us; speedup 1.0000x reference)
//
#include <hip/hip_runtime.h>
#include <math.h>

// One wave = one sample's 10-qubit state. Amplitude i in [0,1024):
//   bits 0..5 -> lane, bits 6..9 -> register index (16 complex/lane).
// Layer = fused U_q = RX(theta)*RY(enc) per qubit, then CNOT chain collapsed
// to the permutation src(j) = j ^ ((j&511)<<1).
// Round-4 change: evacuate the LDS pipe. Param broadcast via v_readlane
// (was ds_bpermute), lane^4 via DPP half_mirror∘quad_perm(xor3), lane^16/32
// via gfx950 v_permlane16/32_swap (VALU). Only the 3 CNOT permutation
// rounds (96 ds_bpermute) remain on the DS pipe.
// Evidence: r3 had ~408 DS ops/wave, 2 waves/SIMD, VALUBusy 28% -> ~90%
// stall = DS latency exposure at low occupancy.

#define PI_F 3.14159265358979323846f

typedef unsigned v2u __attribute__((ext_vector_type(2)));

#if defined(__has_builtin)
#if __has_builtin(__builtin_amdgcn_permlane16_swap)
#define HAVE_PL16 1
#endif
#if __has_builtin(__builtin_amdgcn_permlane32_swap)
#define HAVE_PL32 1
#endif
#endif

__device__ __forceinline__ float rdlane(float v, int l) {
    return __int_as_float(__builtin_amdgcn_readlane(__float_as_int(v), l));
}

// ---- VALU-pipe lane^mask partners (DPP / permlane swap) ----
__device__ __forceinline__ float xor1p(float v) {   // quad_perm [1,0,3,2]
    return __int_as_float(__builtin_amdgcn_update_dpp(
        0, __float_as_int(v), 0xB1, 0xF, 0xF, true));
}
__device__ __forceinline__ float xor2p(float v) {   // quad_perm [2,3,0,1]
    return __int_as_float(__builtin_amdgcn_update_dpp(
        0, __float_as_int(v), 0x4E, 0xF, 0xF, true));
}
__device__ __forceinline__ float xor4p(float v) {   // xor7 ∘ xor3 = xor4
    int t = __builtin_amdgcn_update_dpp(0, __float_as_int(v), 0x1B, 0xF, 0xF, true);  // quad_perm [3,2,1,0]
    t = __builtin_amdgcn_update_dpp(0, t, 0x141, 0xF, 0xF, true);                     // row_half_mirror (lane^7)
    return __int_as_float(t);
}
__device__ __forceinline__ float xor8p(float v) {   // row_ror:8 == lane^8 in 16-row
    return __int_as_float(__builtin_amdgcn_update_dpp(
        0, __float_as_int(v), 0x128, 0xF, 0xF, true));
}
__device__ __forceinline__ float xor16p(float v, bool hi) {
#ifdef HAVE_PL16
    // swap-with-self: r[0]=even-row data in both rows of pair, r[1]=odd-row data
    v2u r = __builtin_amdgcn_permlane16_swap(
        (unsigned)__float_as_int(v), (unsigned)__float_as_int(v), false, false);
    return __int_as_float((int)(hi ? r.x : r.y));
#else
    return __shfl_xor(v, 16);
#endif
}
__device__ __forceinline__ float xor32p(float v, bool hi) {
#ifdef HAVE_PL32
    v2u r = __builtin_amdgcn_permlane32_swap(
        (unsigned)__float_as_int(v), (unsigned)__float_as_int(v), false, false);
    return __int_as_float((int)(hi ? r.x : r.y));
#else
    return __shfl_xor(v, 32);
#endif
}

template<int Q>
__device__ __forceinline__ void lane_gate(float (&sr)[16], float (&si)[16], int lane,
                                          float ar, float ai, float br, float bi) {
    const bool hi = (lane & (1 << Q)) != 0;
    const float aiL = hi ? -ai : ai;   // bit=1 row uses conj(A), -conj(B)
    const float brL = hi ? -br : br;
    #pragma unroll
    for (int r = 0; r < 16; ++r) {
        float pr, pi;
        if constexpr (Q == 0)      { pr = xor1p(sr[r]);      pi = xor1p(si[r]); }
        else if constexpr (Q == 1) { pr = xor2p(sr[r]);      pi = xor2p(si[r]); }
        else if constexpr (Q == 2) { pr = xor4p(sr[r]);      pi = xor4p(si[r]); }
        else if constexpr (Q == 3) { pr = xor8p(sr[r]);      pi = xor8p(si[r]); }
        else if constexpr (Q == 4) { pr = xor16p(sr[r], hi); pi = xor16p(si[r], hi); }
        else                       { pr = xor32p(sr[r], hi); pi = xor32p(si[r], hi); }
        const float vr = sr[r], vi = si[r];
        sr[r] = ar * vr - aiL * vi + brL * pr - bi * pi;
        si[r] = ar * vi + aiL * vr + brL * pi + bi * pr;
    }
}

template<int RB>
__device__ __forceinline__ void reg_gate(float (&sr)[16], float (&si)[16],
                                         float ar, float ai, float br, float bi) {
    #pragma unroll
    for (int r = 0; r < 16; ++r) {
        if ((r & RB) == 0) {
            const int r1 = r | RB;
            const float s0r = sr[r],  s0i = si[r];
            const float s1r = sr[r1], s1i = si[r1];
            sr[r]  = ar * s0r - ai * s0i + br * s1r - bi * s1i;
            si[r]  = ar * s0i + ai * s0r + br * s1i + bi * s1r;
            sr[r1] = ar * s1r + ai * s1i - br * s0r - bi * s0i;
            si[r1] = ar * s1i - ai * s1r - br * s0i + bi * s0r;
        }
    }
}

__device__ __forceinline__ void cnot_chain(float (&sr)[16], float (&si)[16], int lane) {
    // new[j] = old[j ^ ((j&511)<<1)]
    const int srcLane = lane ^ ((lane & 31) << 1);
    float tr[16], ti[16];
    #pragma unroll
    for (int r = 0; r < 16; ++r) {
        tr[r] = __shfl(sr[r], srcLane);
        ti[r] = __shfl(si[r], srcLane);
    }
    const bool b5 = (lane & 32) != 0;   // lane bit5 feeds src reg bit0
    #pragma unroll
    for (int r = 0; r < 16; ++r) {
        const int q0 = r ^ ((r & 7) << 1);
        const int q1 = q0 ^ 1;
        sr[r] = b5 ? tr[q1] : tr[q0];
        si[r] = b5 ? ti[q1] : ti[q0];
    }
}

__global__ __launch_bounds__(256, 1) void cqv_kernel(
    const float* __restrict__ x,
    const float* __restrict__ theta,
    const float* __restrict__ alpha_raw,
    const float* __restrict__ beta_raw,
    const float* __restrict__ head_w,
    const float* __restrict__ head_b,
    const float* __restrict__ logit_scale,
    float* __restrict__ out,
    int batch)
{
    const int lane = threadIdx.x & 63;
    const int wave = threadIdx.x >> 6;
    const int s = blockIdx.x * (blockDim.x >> 6) + wave;
    if (s >= batch) return;

    // per-lane gate params: lane g in [0,30) holds gate g = layer*10 + qubit
    const int g = (lane < 30) ? lane : 0;
    const float alpha = log1pf(expf(alpha_raw[g])) + 1e-6f;
    const float beta  = tanhf(beta_raw[g]);
    const float halfE = 0.5f * PI_F * (alpha * x[s * 49 + g] + beta);
    const float cE = cosf(halfE), sE = sinf(halfE);
    const float th = 0.5f * theta[g];
    const float cT = cosf(th), sT = sinf(th);

    float sr[16], si[16];

    // ---- layer 0 on |0..0>: product state from U columns u(0)=A, u(1)=-conj(B)
    {
        float u0r[10], u0i[10], u1r[10], u1i[10];
        #pragma unroll
        for (int q = 0; q < 10; ++q) {
            const float ce = rdlane(cE, q), se = rdlane(sE, q);
            const float ct = rdlane(cT, q), st = rdlane(sT, q);
            u0r[q] = ct * ce;  u0i[q] = -st * se;   // A
            u1r[q] = ct * se;  u1i[q] = -st * ce;   // -conj(B)
        }
        float plr = 1.f, pli = 0.f;                 // product over lane bits 0..5
        #pragma unroll
        for (int q = 0; q < 6; ++q) {
            const bool bq = (lane >> q) & 1;
            const float wr = bq ? u1r[q] : u0r[q];
            const float wi = bq ? u1i[q] : u0i[q];
            const float nr = plr * wr - pli * wi;
            const float ni = plr * wi + pli * wr;
            plr = nr; pli = ni;
        }
        float t67r[4], t67i[4], t89r[4], t89i[4];   // reg bits: b0<->q6 .. b3<->q9
        #pragma unroll
        for (int a = 0; a < 4; ++a) {
            const float w6r = (a & 1) ? u1r[6] : u0r[6], w6i = (a & 1) ? u1i[6] : u0i[6];
            const float w7r = (a & 2) ? u1r[7] : u0r[7], w7i = (a & 2) ? u1i[7] : u0i[7];
            t67r[a] = w6r * w7r - w6i * w7i;  t67i[a] = w6r * w7i + w6i * w7r;
            const float w8r = (a & 1) ? u1r[8] : u0r[8], w8i = (a & 1) ? u1i[8] : u0i[8];
            const float w9r = (a & 2) ? u1r[9] : u0r[9], w9i = (a & 2) ? u1i[9] : u0i[9];
            t89r[a] = w8r * w9r - w8i * w9i;  t89i[a] = w8r * w9i + w8i * w9r;
        }
        #pragma unroll
        for (int r = 0; r < 16; ++r) {
            const float ar = t67r[r & 3] * t89r[r >> 2] - t67i[r & 3] * t89i[r >> 2];
            const float ai = t67r[r & 3] * t89i[r >> 2] + t67i[r & 3] * t89r[r >> 2];
            sr[r] = ar * plr - ai * pli;
            si[r] = ar * pli + ai * plr;
        }
    }
    cnot_chain(sr, si, lane);

    // ---- layers 1,2: rolled loop (I$-resident); params via readlane (JIT,
    // 4 live uniforms at a time -> no SGPR blowup) ----
    #pragma unroll 1
    for (int b = 1; b < 3; ++b) {
        const int base = b * 10;
#define GATE_PARAMS(Q) \
        const float ce = rdlane(cE, base + (Q)), se = rdlane(sE, base + (Q)); \
        const float ct = rdlane(cT, base + (Q)), st = rdlane(sT, base + (Q));
#define APPLY_LANE_GATE(Q) { GATE_PARAMS(Q) \
        lane_gate<Q>(sr, si, lane, ct * ce, -st * se, -ct * se, -st * ce); }
#define APPLY_REG_GATE(Q, RB) { GATE_PARAMS(Q) \
        reg_gate<RB>(sr, si, ct * ce, -st * se, -ct * se, -st * ce); }
        APPLY_LANE_GATE(0)
        APPLY_LANE_GATE(1)
        APPLY_LANE_GATE(2)
        APPLY_LANE_GATE(3)
        APPLY_LANE_GATE(4)
        APPLY_LANE_GATE(5)
        APPLY_REG_GATE(6, 1)
        APPLY_REG_GATE(7, 2)
        APPLY_REG_GATE(8, 4)
        APPLY_REG_GATE(9, 8)
#undef GATE_PARAMS
#undef APPLY_LANE_GATE
#undef APPLY_REG_GATE
        cnot_chain(sr, si, lane);
    }

    // ---- epilogue: <Z> head. W(i) = sum_q w_q*(1-2*bit_q(i)) ----
    float w[10];
    #pragma unroll
    for (int q = 0; q < 10; ++q) w[q] = head_w[q];
    float wlane = 0.f;
    #pragma unroll
    for (int q = 0; q < 6; ++q) wlane += ((lane >> q) & 1) ? -w[q] : w[q];
    float acc = 0.f, psum = 0.f;
    #pragma unroll
    for (int r = 0; r < 16; ++r) {
        const float p = sr[r] * sr[r] + si[r] * si[r];
        const float wr = ((r & 1) ? -w[6] : w[6]) + ((r & 2) ? -w[7] : w[7])
                       + ((r & 4) ? -w[8] : w[8]) + ((r & 8) ? -w[9] : w[9]);
        psum += p;
        acc = fmaf(wr, p, acc);
    }
    float partial = fmaf(wlane, psum, acc);
    #pragma unroll
    for (int off = 32; off >= 1; off >>= 1) partial += __shfl_xor(partial, off);

    if (lane == 0) {
        const float scale = fminf(fmaxf(logit_scale[0], 0.5f), 80.f);
        const float raw = partial + head_b[0];
        out[s] = fminf(fmaxf(scale * raw, -30.f), 30.f);
    }
}

extern "C" void kernel_launch(void* const* d_in, const int* in_sizes, int n_in,
                              void* d_out, int out_size, void* d_ws, size_t ws_size,
                              hipStream_t stream) {
    const int B = in_sizes[0] / 49;          // BATCH = 2048
    const int WPB = 4;
    dim3 block(64 * WPB);
    dim3 grid((B + WPB - 1) / WPB);
    cqv_kernel<<<grid, block, 0, stream>>>(
        (const float*)d_in[0], (const float*)d_in[1], (const float*)d_in[2],
        (const float*)d_in[3], (const float*)d_in[4], (const float*)d_in[5],
        (const float*)d_in[6], (float*)d_out, B);
}

// Round 5
// 84.709 us; speedup vs baseline: 1.0758x; 1.0758x over previous
//
#include <hip/hip_runtime.h>
#include <math.h>

// One wave = one sample's 10-qubit state. Amplitude i in [0,1024):
//   bits 0..5 -> lane, bits 6..9 -> register index (16 complex/lane, float2).
// Layer = fused U_q = RX(theta)*RY(enc) per qubit, then CNOT chain collapsed
// to the permutation src(j) = j ^ ((j&511)<<1).
// Round-5 change: state stored as float2 (re,im) pairs; gate cores use
// v_pk_fma_f32 (2 FMA/issue) with op_sel/neg modifiers forming the
// (-im,re) operand for free. Cuts ~2560 scalar FMA -> ~1280 pk ops.
// Evidence: r4 (DS->VALU swap, op-count neutral) was dur-neutral => kernel is
// issue-count-bound, not pipe-bound. Only total-op reduction helps.

#define PI_F 3.14159265358979323846f

typedef unsigned v2u __attribute__((ext_vector_type(2)));

#if defined(__has_builtin)
#if __has_builtin(__builtin_amdgcn_permlane16_swap)
#define HAVE_PL16 1
#endif
#if __has_builtin(__builtin_amdgcn_permlane32_swap)
#define HAVE_PL32 1
#endif
#endif

__device__ __forceinline__ float rdlane(float v, int l) {
    return __int_as_float(__builtin_amdgcn_readlane(__float_as_int(v), l));
}

// ---- VALU-pipe lane^mask partner fetch (component-wise, from r4: exact) ----
__device__ __forceinline__ float xor1p(float v) {   // quad_perm [1,0,3,2]
    return __int_as_float(__builtin_amdgcn_update_dpp(
        0, __float_as_int(v), 0xB1, 0xF, 0xF, true));
}
__device__ __forceinline__ float xor2p(float v) {   // quad_perm [2,3,0,1]
    return __int_as_float(__builtin_amdgcn_update_dpp(
        0, __float_as_int(v), 0x4E, 0xF, 0xF, true));
}
__device__ __forceinline__ float xor4p(float v) {   // xor7 ∘ xor3 = xor4
    int t = __builtin_amdgcn_update_dpp(0, __float_as_int(v), 0x1B, 0xF, 0xF, true);
    t = __builtin_amdgcn_update_dpp(0, t, 0x141, 0xF, 0xF, true);
    return __int_as_float(t);
}
__device__ __forceinline__ float xor8p(float v) {   // row_ror:8
    return __int_as_float(__builtin_amdgcn_update_dpp(
        0, __float_as_int(v), 0x128, 0xF, 0xF, true));
}
__device__ __forceinline__ float xor16p(float v, bool hi) {
#ifdef HAVE_PL16
    v2u r = __builtin_amdgcn_permlane16_swap(
        (unsigned)__float_as_int(v), (unsigned)__float_as_int(v), false, false);
    return __int_as_float((int)(hi ? r.x : r.y));
#else
    return __shfl_xor(v, 16);
#endif
}
__device__ __forceinline__ float xor32p(float v, bool hi) {
#ifdef HAVE_PL32
    v2u r = __builtin_amdgcn_permlane32_swap(
        (unsigned)__float_as_int(v), (unsigned)__float_as_int(v), false, false);
    return __int_as_float((int)(hi ? r.x : r.y));
#else
    return __shfl_xor(v, 32);
#endif
}

template<int Q>
__device__ __forceinline__ float lane_xor(float v, bool hi) {
    if constexpr (Q == 0) return xor1p(v);
    else if constexpr (Q == 1) return xor2p(v);
    else if constexpr (Q == 2) return xor4p(v);
    else if constexpr (Q == 3) return xor8p(v);
    else if constexpr (Q == 4) return xor16p(v, hi);
    else return xor32p(v, hi);
}

// ---- packed complex gate core: acc = A*v + B*w (per amp, 4 pk ops) ----
// lo = ar*v.x - ai*v.y + br*w.x - bi*w.y ; hi = ar*v.y + ai*v.x + br*w.y + bi*w.x
// NEG=true flips the sign of the ai and br coefficients (select-bit=1 row).
template<bool NEG>
__device__ __forceinline__ float2 cgate(const float2 ar2, const float2 ai2,
                                        const float2 br2, const float2 bi2,
                                        const float2 v, const float2 w) {
    float2 acc;
    asm("v_pk_mul_f32 %0, %1, %2" : "=v"(acc) : "v"(ar2), "v"(v));
    if constexpr (!NEG) {
        asm("v_pk_fma_f32 %0, %1, %2, %0 op_sel:[0,1,0] op_sel_hi:[1,0,1] neg_lo:[0,1,0]"
            : "+v"(acc) : "v"(ai2), "v"(v));
        asm("v_pk_fma_f32 %0, %1, %2, %0" : "+v"(acc) : "v"(br2), "v"(w));
    } else {
        asm("v_pk_fma_f32 %0, %1, %2, %0 op_sel:[0,1,0] op_sel_hi:[1,0,1] neg_lo:[1,1,0] neg_hi:[1,0,0]"
            : "+v"(acc) : "v"(ai2), "v"(v));
        asm("v_pk_fma_f32 %0, %1, %2, %0 neg_lo:[1,0,0] neg_hi:[1,0,0]"
            : "+v"(acc) : "v"(br2), "v"(w));
    }
    asm("v_pk_fma_f32 %0, %1, %2, %0 op_sel:[0,1,0] op_sel_hi:[1,0,1] neg_lo:[0,1,0]"
        : "+v"(acc) : "v"(bi2), "v"(w));
    return acc;
}

template<int Q>
__device__ __forceinline__ void lane_gate(float2 (&st)[16], int lane,
                                          float ar, float ai, float br, float bi) {
    const bool hi = (lane & (1 << Q)) != 0;
    const float aiL = hi ? -ai : ai;   // bit=1 row uses conj(A), -conj(B)
    const float brL = hi ? -br : br;
    const float2 ar2 = make_float2(ar, ar);
    const float2 ai2 = make_float2(aiL, aiL);
    const float2 br2 = make_float2(brL, brL);
    const float2 bi2 = make_float2(bi, bi);
    #pragma unroll
    for (int r = 0; r < 16; ++r) {
        float2 p;
        p.x = lane_xor<Q>(st[r].x, hi);
        p.y = lane_xor<Q>(st[r].y, hi);
        st[r] = cgate<false>(ar2, ai2, br2, bi2, st[r], p);
    }
}

template<int RB>
__device__ __forceinline__ void reg_gate(float2 (&st)[16],
                                         float ar, float ai, float br, float bi) {
    const float2 ar2 = make_float2(ar, ar);
    const float2 ai2 = make_float2(ai, ai);
    const float2 br2 = make_float2(br, br);
    const float2 bi2 = make_float2(bi, bi);
    #pragma unroll
    for (int r = 0; r < 16; ++r) {
        if ((r & RB) == 0) {
            const int r1 = r | RB;
            const float2 v0 = st[r], v1 = st[r1];
            st[r]  = cgate<false>(ar2, ai2, br2, bi2, v0, v1);  // select=0 row
            st[r1] = cgate<true >(ar2, ai2, br2, bi2, v1, v0);  // select=1 row
        }
    }
}

__device__ __forceinline__ void cnot_chain(float2 (&st)[16], int lane) {
    // new[j] = old[j ^ ((j&511)<<1)]
    const int srcLane = lane ^ ((lane & 31) << 1);
    float2 t[16];
    #pragma unroll
    for (int r = 0; r < 16; ++r) {
        t[r].x = __shfl(st[r].x, srcLane);
        t[r].y = __shfl(st[r].y, srcLane);
    }
    const bool b5 = (lane & 32) != 0;   // lane bit5 feeds src reg bit0
    #pragma unroll
    for (int r = 0; r < 16; ++r) {
        const int q0 = r ^ ((r & 7) << 1);
        const int q1 = q0 ^ 1;
        st[r] = b5 ? t[q1] : t[q0];
    }
}

__global__ __launch_bounds__(256, 1) void cqv_kernel(
    const float* __restrict__ x,
    const float* __restrict__ theta,
    const float* __restrict__ alpha_raw,
    const float* __restrict__ beta_raw,
    const float* __restrict__ head_w,
    const float* __restrict__ head_b,
    const float* __restrict__ logit_scale,
    float* __restrict__ out,
    int batch)
{
    const int lane = threadIdx.x & 63;
    const int wave = threadIdx.x >> 6;
    const int s = blockIdx.x * (blockDim.x >> 6) + wave;
    if (s >= batch) return;

    // per-lane gate params: lane g in [0,30) holds gate g = layer*10 + qubit
    const int g = (lane < 30) ? lane : 0;
    const float alpha = log1pf(__expf(alpha_raw[g])) + 1e-6f;
    const float beta  = tanhf(beta_raw[g]);
    const float halfE = 0.5f * PI_F * (alpha * x[s * 49 + g] + beta);
    float cE, sE, cT, sT;
    __sincosf(halfE, &sE, &cE);
    __sincosf(0.5f * theta[g], &sT, &cT);

    float2 st[16];

    // ---- layer 0 on |0..0>: product state from U columns u(0)=A, u(1)=-conj(B)
    {
        float u0r[10], u0i[10], u1r[10], u1i[10];
        #pragma unroll
        for (int q = 0; q < 10; ++q) {
            const float ce = rdlane(cE, q), se = rdlane(sE, q);
            const float ct = rdlane(cT, q), s_t = rdlane(sT, q);
            u0r[q] = ct * ce;  u0i[q] = -s_t * se;   // A
            u1r[q] = ct * se;  u1i[q] = -s_t * ce;   // -conj(B)
        }
        float plr = 1.f, pli = 0.f;                  // product over lane bits 0..5
        #pragma unroll
        for (int q = 0; q < 6; ++q) {
            const bool bq = (lane >> q) & 1;
            const float wr = bq ? u1r[q] : u0r[q];
            const float wi = bq ? u1i[q] : u0i[q];
            const float nr = plr * wr - pli * wi;
            const float ni = plr * wi + pli * wr;
            plr = nr; pli = ni;
        }
        float t67r[4], t67i[4], t89r[4], t89i[4];    // reg bits: b0<->q6 .. b3<->q9
        #pragma unroll
        for (int a = 0; a < 4; ++a) {
            const float w6r = (a & 1) ? u1r[6] : u0r[6], w6i = (a & 1) ? u1i[6] : u0i[6];
            const float w7r = (a & 2) ? u1r[7] : u0r[7], w7i = (a & 2) ? u1i[7] : u0i[7];
            t67r[a] = w6r * w7r - w6i * w7i;  t67i[a] = w6r * w7i + w6i * w7r;
            const float w8r = (a & 1) ? u1r[8] : u0r[8], w8i = (a & 1) ? u1i[8] : u0i[8];
            const float w9r = (a & 2) ? u1r[9] : u0r[9], w9i = (a & 2) ? u1i[9] : u0i[9];
            t89r[a] = w8r * w9r - w8i * w9i;  t89i[a] = w8r * w9i + w8i * w9r;
        }
        #pragma unroll
        for (int r = 0; r < 16; ++r) {
            const float ar = t67r[r & 3] * t89r[r >> 2] - t67i[r & 3] * t89i[r >> 2];
            const float ai = t67r[r & 3] * t89i[r >> 2] + t67i[r & 3] * t89r[r >> 2];
            st[r].x = ar * plr - ai * pli;
            st[r].y = ar * pli + ai * plr;
        }
    }
    cnot_chain(st, lane);

    // ---- layers 1,2: rolled loop (I$-resident); params via readlane ----
    #pragma unroll 1
    for (int b = 1; b < 3; ++b) {
        const int base = b * 10;
#define GATE_PARAMS(Q) \
        const float ce = rdlane(cE, base + (Q)), se = rdlane(sE, base + (Q)); \
        const float ct = rdlane(cT, base + (Q)), s_t = rdlane(sT, base + (Q));
#define APPLY_LANE_GATE(Q) { GATE_PARAMS(Q) \
        lane_gate<Q>(st, lane, ct * ce, -s_t * se, -ct * se, -s_t * ce); }
#define APPLY_REG_GATE(Q, RB) { GATE_PARAMS(Q) \
        reg_gate<RB>(st, ct * ce, -s_t * se, -ct * se, -s_t * ce); }
        APPLY_LANE_GATE(0)
        APPLY_LANE_GATE(1)
        APPLY_LANE_GATE(2)
        APPLY_LANE_GATE(3)
        APPLY_LANE_GATE(4)
        APPLY_LANE_GATE(5)
        APPLY_REG_GATE(6, 1)
        APPLY_REG_GATE(7, 2)
        APPLY_REG_GATE(8, 4)
        APPLY_REG_GATE(9, 8)
#undef GATE_PARAMS
#undef APPLY_LANE_GATE
#undef APPLY_REG_GATE
        cnot_chain(st, lane);
    }

    // ---- epilogue: <Z> head. W(i) = sum_q w_q*(1-2*bit_q(i)) ----
    float w[10];
    #pragma unroll
    for (int q = 0; q < 10; ++q) w[q] = head_w[q];
    float wlane = 0.f;
    #pragma unroll
    for (int q = 0; q < 6; ++q) wlane += ((lane >> q) & 1) ? -w[q] : w[q];
    float acc = 0.f, psum = 0.f;
    #pragma unroll
    for (int r = 0; r < 16; ++r) {
        const float p = st[r].x * st[r].x + st[r].y * st[r].y;
        const float wr = ((r & 1) ? -w[6] : w[6]) + ((r & 2) ? -w[7] : w[7])
                       + ((r & 4) ? -w[8] : w[8]) + ((r & 8) ? -w[9] : w[9]);
        psum += p;
        acc = fmaf(wr, p, acc);
    }
    float partial = fmaf(wlane, psum, acc);
    #pragma unroll
    for (int off = 32; off >= 1; off >>= 1) partial += __shfl_xor(partial, off);

    if (lane == 0) {
        const float scale = fminf(fmaxf(logit_scale[0], 0.5f), 80.f);
        const float raw = partial + head_b[0];
        out[s] = fminf(fmaxf(scale * raw, -30.f), 30.f);
    }
}

extern "C" void kernel_launch(void* const* d_in, const int* in_sizes, int n_in,
                              void* d_out, int out_size, void* d_ws, size_t ws_size,
                              hipStream_t stream) {
    const int B = in_sizes[0] / 49;          // BATCH = 2048
    const int WPB = 4;
    dim3 block(64 * WPB);
    dim3 grid((B + WPB - 1) / WPB);
    cqv_kernel<<<grid, block, 0, stream>>>(
        (const float*)d_in[0], (const float*)d_in[1], (const float*)d_in[2],
        (const float*)d_in[3], (const float*)d_in[4], (const float*)d_in[5],
        (const float*)d_in[6], (float*)d_out, B);
}

// Round 6
// 81.230 us; speedup vs baseline: 1.1219x; 1.0428x over previous
//
#include <hip/hip_runtime.h>
#include <math.h>

// TWO waves per sample: qubit 9 = wave bit. Amplitude i in [0,1024):
//   bits 0..5 -> lane, bits 6..8 -> register (8 float2/lane), bit 9 -> wave.
// Per layer: fused U_q = RX(theta)*RY(enc) on q0..q8 in-wave; the q9 gate is
// FUSED into the CNOT-chain permutation src(j) = j ^ ((j&511)<<1) via one
// double-buffered LDS exchange: new[j] = (U9 psi)[src(j)], reading both
// waves' source amplitudes. 1 barrier/layer + 1 for the epilogue combine.
// Rationale: r5 showed kernel <40us at 2 waves/SIMD, latency-exposed
// (pk_fma -28% insts -> only -7% dur). This doubles occupancy (4/SIMD) and
// halves the per-wave dependency chain.

#define PI_F 3.14159265358979323846f

typedef unsigned v2u __attribute__((ext_vector_type(2)));

#if defined(__has_builtin)
#if __has_builtin(__builtin_amdgcn_permlane16_swap)
#define HAVE_PL16 1
#endif
#if __has_builtin(__builtin_amdgcn_permlane32_swap)
#define HAVE_PL32 1
#endif
#endif

__device__ __forceinline__ float rdlane(float v, int l) {
    return __int_as_float(__builtin_amdgcn_readlane(__float_as_int(v), l));
}

// ---- VALU-pipe lane^mask partner fetch (verified r4/r5, absmax 0) ----
__device__ __forceinline__ float xor1p(float v) {
    return __int_as_float(__builtin_amdgcn_update_dpp(
        0, __float_as_int(v), 0xB1, 0xF, 0xF, true));
}
__device__ __forceinline__ float xor2p(float v) {
    return __int_as_float(__builtin_amdgcn_update_dpp(
        0, __float_as_int(v), 0x4E, 0xF, 0xF, true));
}
__device__ __forceinline__ float xor4p(float v) {   // xor7 ∘ xor3 = xor4
    int t = __builtin_amdgcn_update_dpp(0, __float_as_int(v), 0x1B, 0xF, 0xF, true);
    t = __builtin_amdgcn_update_dpp(0, t, 0x141, 0xF, 0xF, true);
    return __int_as_float(t);
}
__device__ __forceinline__ float xor8p(float v) {   // row_ror:8
    return __int_as_float(__builtin_amdgcn_update_dpp(
        0, __float_as_int(v), 0x128, 0xF, 0xF, true));
}
__device__ __forceinline__ float xor16p(float v, bool hi) {
#ifdef HAVE_PL16
    v2u r = __builtin_amdgcn_permlane16_swap(
        (unsigned)__float_as_int(v), (unsigned)__float_as_int(v), false, false);
    return __int_as_float((int)(hi ? r.x : r.y));
#else
    return __shfl_xor(v, 16);
#endif
}
__device__ __forceinline__ float xor32p(float v, bool hi) {
#ifdef HAVE_PL32
    v2u r = __builtin_amdgcn_permlane32_swap(
        (unsigned)__float_as_int(v), (unsigned)__float_as_int(v), false, false);
    return __int_as_float((int)(hi ? r.x : r.y));
#else
    return __shfl_xor(v, 32);
#endif
}

template<int Q>
__device__ __forceinline__ float lane_xor(float v, bool hi) {
    if constexpr (Q == 0) return xor1p(v);
    else if constexpr (Q == 1) return xor2p(v);
    else if constexpr (Q == 2) return xor4p(v);
    else if constexpr (Q == 3) return xor8p(v);
    else if constexpr (Q == 4) return xor16p(v, hi);
    else return xor32p(v, hi);
}

// ---- packed complex gate core (verified r5, absmax 0) ----
template<bool NEG>
__device__ __forceinline__ float2 cgate(const float2 ar2, const float2 ai2,
                                        const float2 br2, const float2 bi2,
                                        const float2 v, const float2 w) {
    float2 acc;
    asm("v_pk_mul_f32 %0, %1, %2" : "=v"(acc) : "v"(ar2), "v"(v));
    if constexpr (!NEG) {
        asm("v_pk_fma_f32 %0, %1, %2, %0 op_sel:[0,1,0] op_sel_hi:[1,0,1] neg_lo:[0,1,0]"
            : "+v"(acc) : "v"(ai2), "v"(v));
        asm("v_pk_fma_f32 %0, %1, %2, %0" : "+v"(acc) : "v"(br2), "v"(w));
    } else {
        asm("v_pk_fma_f32 %0, %1, %2, %0 op_sel:[0,1,0] op_sel_hi:[1,0,1] neg_lo:[1,1,0] neg_hi:[1,0,0]"
            : "+v"(acc) : "v"(ai2), "v"(v));
        asm("v_pk_fma_f32 %0, %1, %2, %0 neg_lo:[1,0,0] neg_hi:[1,0,0]"
            : "+v"(acc) : "v"(br2), "v"(w));
    }
    asm("v_pk_fma_f32 %0, %1, %2, %0 op_sel:[0,1,0] op_sel_hi:[1,0,1] neg_lo:[0,1,0]"
        : "+v"(acc) : "v"(bi2), "v"(w));
    return acc;
}

template<int Q>
__device__ __forceinline__ void lane_gate(float2 (&st)[8], int lane,
                                          float ar, float ai, float br, float bi) {
    const bool hi = (lane & (1 << Q)) != 0;
    const float aiL = hi ? -ai : ai;
    const float brL = hi ? -br : br;
    const float2 ar2 = make_float2(ar, ar);
    const float2 ai2 = make_float2(aiL, aiL);
    const float2 br2 = make_float2(brL, brL);
    const float2 bi2 = make_float2(bi, bi);
    #pragma unroll
    for (int r = 0; r < 8; ++r) {
        float2 p;
        p.x = lane_xor<Q>(st[r].x, hi);
        p.y = lane_xor<Q>(st[r].y, hi);
        st[r] = cgate<false>(ar2, ai2, br2, bi2, st[r], p);
    }
}

template<int RB>
__device__ __forceinline__ void reg_gate(float2 (&st)[8],
                                         float ar, float ai, float br, float bi) {
    const float2 ar2 = make_float2(ar, ar);
    const float2 ai2 = make_float2(ai, ai);
    const float2 br2 = make_float2(br, br);
    const float2 bi2 = make_float2(bi, bi);
    #pragma unroll
    for (int r = 0; r < 8; ++r) {
        if ((r & RB) == 0) {
            const int r1 = r | RB;
            const float2 v0 = st[r], v1 = st[r1];
            st[r]  = cgate<false>(ar2, ai2, br2, bi2, v0, v1);
            st[r1] = cgate<true >(ar2, ai2, br2, bi2, v1, v0);
        }
    }
}

__global__ __launch_bounds__(256, 4) void cqv_kernel(
    const float* __restrict__ x,
    const float* __restrict__ theta,
    const float* __restrict__ alpha_raw,
    const float* __restrict__ beta_raw,
    const float* __restrict__ head_w,
    const float* __restrict__ head_b,
    const float* __restrict__ logit_scale,
    float* __restrict__ out,
    int batch)
{
    const int lane = threadIdx.x & 63;
    const int wavid = threadIdx.x >> 6;        // 0..3
    const int p  = wavid >> 1;                 // sample-pair within block
    const int wv = wavid & 1;                  // qubit-9 bit of this wave
    const int s = blockIdx.x * 2 + p;
    if (s >= batch) return;

    // [dbuf][pair][reg][wv][lane] ; + epilogue partials
    __shared__ float2 lds[2][2][8][2][64];
    __shared__ float pbuf[2][2];

    const int l5 = (lane >> 5) & 1;
    const int srcLane = lane ^ ((lane & 31) << 1);

    // ---- per-lane gate params: lane g holds gate g = layer*10 + qubit ----
    const int g = (lane < 30) ? lane : 0;
    const float alpha = log1pf(__expf(alpha_raw[g])) + 1e-6f;
    const float beta  = tanhf(beta_raw[g]);
    const float halfE = 0.5f * PI_F * (alpha * x[s * 49 + g] + beta);
    float cE, sE, cT, sT;
    __sincosf(halfE, &sE, &cE);
    __sincosf(0.5f * theta[g], &sT, &cT);

    float2 st[8];

    // ---- layer 0 on |0..0>: product state, q9 factor chosen by wv ----
    {
        float u0r[10], u0i[10], u1r[10], u1i[10];
        #pragma unroll
        for (int q = 0; q < 10; ++q) {
            const float ce = rdlane(cE, q), se = rdlane(sE, q);
            const float ct = rdlane(cT, q), s_t = rdlane(sT, q);
            u0r[q] = ct * ce;  u0i[q] = -s_t * se;   // A
            u1r[q] = ct * se;  u1i[q] = -s_t * ce;   // -conj(B)
        }
        float plr = 1.f, pli = 0.f;                  // lane bits 0..5
        #pragma unroll
        for (int q = 0; q < 6; ++q) {
            const bool bq = (lane >> q) & 1;
            const float wr = bq ? u1r[q] : u0r[q];
            const float wi = bq ? u1i[q] : u0i[q];
            const float nr = plr * wr - pli * wi;
            const float ni = plr * wi + pli * wr;
            plr = nr; pli = ni;
        }
        // fold q9 (by wv) into the q8 pair
        const float w9r = wv ? u1r[9] : u0r[9], w9i = wv ? u1i[9] : u0i[9];
        float t67r[4], t67i[4], t89r[2], t89i[2];
        #pragma unroll
        for (int a = 0; a < 4; ++a) {
            const float w6r = (a & 1) ? u1r[6] : u0r[6], w6i = (a & 1) ? u1i[6] : u0i[6];
            const float w7r = (a & 2) ? u1r[7] : u0r[7], w7i = (a & 2) ? u1i[7] : u0i[7];
            t67r[a] = w6r * w7r - w6i * w7i;  t67i[a] = w6r * w7i + w6i * w7r;
        }
        #pragma unroll
        for (int k = 0; k < 2; ++k) {
            const float w8r = k ? u1r[8] : u0r[8], w8i = k ? u1i[8] : u0i[8];
            t89r[k] = w8r * w9r - w8i * w9i;  t89i[k] = w8r * w9i + w8i * w9r;
        }
        #pragma unroll
        for (int r = 0; r < 8; ++r) {
            const float ar = t67r[r & 3] * t89r[r >> 2] - t67i[r & 3] * t89i[r >> 2];
            const float ai = t67r[r & 3] * t89i[r >> 2] + t67i[r & 3] * t89r[r >> 2];
            st[r].x = ar * plr - ai * pli;
            st[r].y = ar * pli + ai * plr;
        }
    }

    // ---- layer-0 CNOT chain: pure cross-wave permutation (dbuf 0) ----
    {
        #pragma unroll
        for (int r = 0; r < 8; ++r) lds[0][p][r][wv][lane] = st[r];
        __syncthreads();
        #pragma unroll
        for (int r = 0; r < 8; ++r) {
            const int sReg = (r ^ ((r & 3) << 1)) ^ l5;
            const int k9 = wv ^ (r >> 2);
            st[r] = lds[0][p][sReg][k9][srcLane];
        }
    }

    // ---- layers 1,2: q0..q8 in-wave; q9 gate fused into CNOT exchange ----
    #pragma unroll 1
    for (int b = 1; b < 3; ++b) {
        const int base = b * 10;
#define GATE_PARAMS(Q) \
        const float ce = rdlane(cE, base + (Q)), se = rdlane(sE, base + (Q)); \
        const float ct = rdlane(cT, base + (Q)), s_t = rdlane(sT, base + (Q));
#define APPLY_LANE_GATE(Q) { GATE_PARAMS(Q) \
        lane_gate<Q>(st, lane, ct * ce, -s_t * se, -ct * se, -s_t * ce); }
#define APPLY_REG_GATE(Q, RB) { GATE_PARAMS(Q) \
        reg_gate<RB>(st, ct * ce, -s_t * se, -ct * se, -s_t * ce); }
        APPLY_LANE_GATE(0)
        APPLY_LANE_GATE(1)
        APPLY_LANE_GATE(2)
        APPLY_LANE_GATE(3)
        APPLY_LANE_GATE(4)
        APPLY_LANE_GATE(5)
        APPLY_REG_GATE(6, 1)
        APPLY_REG_GATE(7, 2)
        APPLY_REG_GATE(8, 4)

        // fused q9 gate + CNOT chain through LDS (dbuf alternates 1,0)
        const int db = b & 1;
        GATE_PARAMS(9)
        const float ar = ct * ce, ai = -s_t * se, br = -ct * se, bi = -s_t * ce;
        const float2 ar2 = make_float2(ar, ar), ai2 = make_float2(ai, ai);
        const float2 br2 = make_float2(br, br), bi2 = make_float2(bi, bi);
        #pragma unroll
        for (int r = 0; r < 8; ++r) lds[db][p][r][wv][lane] = st[r];
        __syncthreads();
        #pragma unroll
        for (int r = 0; r < 8; ++r) {
            const int sReg = (r ^ ((r & 3) << 1)) ^ l5;
            const int k9 = wv ^ (r >> 2);           // wave-uniform per r
            const float2 v = lds[db][p][sReg][k9][srcLane];      // pre[k]
            const float2 w = lds[db][p][sReg][k9 ^ 1][srcLane];  // pre[k^bit9]
            if (k9 == 0) st[r] = cgate<false>(ar2, ai2, br2, bi2, v, w);
            else         st[r] = cgate<true >(ar2, ai2, br2, bi2, v, w);
        }
#undef GATE_PARAMS
#undef APPLY_LANE_GATE
#undef APPLY_REG_GATE
    }

    // ---- epilogue: W(i) = wlane(bits0-5) + wreg(bits6-8) + w9*(1-2*wv) ----
    float w[10];
    #pragma unroll
    for (int q = 0; q < 10; ++q) w[q] = head_w[q];
    float wlane = wv ? -w[9] : w[9];
    #pragma unroll
    for (int q = 0; q < 6; ++q) wlane += ((lane >> q) & 1) ? -w[q] : w[q];
    float acc = 0.f, psum = 0.f;
    #pragma unroll
    for (int r = 0; r < 8; ++r) {
        const float pw = st[r].x * st[r].x + st[r].y * st[r].y;
        const float wr = ((r & 1) ? -w[6] : w[6]) + ((r & 2) ? -w[7] : w[7])
                       + ((r & 4) ? -w[8] : w[8]);
        psum += pw;
        acc = fmaf(wr, pw, acc);
    }
    float partial = fmaf(wlane, psum, acc);
    #pragma unroll
    for (int off = 32; off >= 1; off >>= 1) partial += __shfl_xor(partial, off);

    if (lane == 0) pbuf[p][wv] = partial;
    __syncthreads();
    if (lane == 0 && wv == 0) {
        const float scale = fminf(fmaxf(logit_scale[0], 0.5f), 80.f);
        const float raw = pbuf[p][0] + pbuf[p][1] + head_b[0];
        out[s] = fminf(fmaxf(scale * raw, -30.f), 30.f);
    }
}

extern "C" void kernel_launch(void* const* d_in, const int* in_sizes, int n_in,
                              void* d_out, int out_size, void* d_ws, size_t ws_size,
                              hipStream_t stream) {
    const int B = in_sizes[0] / 49;          // BATCH = 2048
    dim3 block(256);                         // 4 waves = 2 samples
    dim3 grid((B + 1) / 2);
    cqv_kernel<<<grid, block, 0, stream>>>(
        (const float*)d_in[0], (const float*)d_in[1], (const float*)d_in[2],
        (const float*)d_in[3], (const float*)d_in[4], (const float*)d_in[5],
        (const float*)d_in[6], (float*)d_out, B);
}

// Round 7
// 79.740 us; speedup vs baseline: 1.1428x; 1.0187x over previous
//
#include <hip/hip_runtime.h>
#include <math.h>

// TWO waves per sample, ONE sample per block (block=128). Amplitude i:
//   bits 0..5 -> lane, bits 6..8 -> register (8 float2/lane), bit 9 -> wave.
// Layers: fused U_q = RX(theta)*RY(enc); CNOT chain = permutation
// src(j) = j ^ ((j&511)<<1). Layer-0 acts on |0..0> -> product state.
// Layer-2's FINAL CNOT chain is absorbed into the head weights via
// prefix-XOR signs (W'(k) = sum_q w_q * (1-2*(k_0^..^k_q))), so the last
// LDS exchange is a trivial same-address pair swap for the q9 gate only.
// Evidence trail: r4 DS->VALU neutral (issue-bound), r5 pk_fma -28% insts
// (win), r6 2-wave split (small win); block-wide barriers coupling 2
// independent samples + the permuted last exchange are the remaining
// serialization this round removes.

#define PI_F 3.14159265358979323846f

typedef unsigned v2u __attribute__((ext_vector_type(2)));

#if defined(__has_builtin)
#if __has_builtin(__builtin_amdgcn_permlane16_swap)
#define HAVE_PL16 1
#endif
#if __has_builtin(__builtin_amdgcn_permlane32_swap)
#define HAVE_PL32 1
#endif
#endif

__device__ __forceinline__ float rdlane(float v, int l) {
    return __int_as_float(__builtin_amdgcn_readlane(__float_as_int(v), l));
}

// ---- VALU-pipe lane^mask partner fetch (verified r4-r6, absmax 0) ----
__device__ __forceinline__ float xor1p(float v) {
    return __int_as_float(__builtin_amdgcn_update_dpp(
        0, __float_as_int(v), 0xB1, 0xF, 0xF, true));
}
__device__ __forceinline__ float xor2p(float v) {
    return __int_as_float(__builtin_amdgcn_update_dpp(
        0, __float_as_int(v), 0x4E, 0xF, 0xF, true));
}
__device__ __forceinline__ float xor4p(float v) {   // xor7 ∘ xor3 = xor4
    int t = __builtin_amdgcn_update_dpp(0, __float_as_int(v), 0x1B, 0xF, 0xF, true);
    t = __builtin_amdgcn_update_dpp(0, t, 0x141, 0xF, 0xF, true);
    return __int_as_float(t);
}
__device__ __forceinline__ float xor8p(float v) {   // row_ror:8
    return __int_as_float(__builtin_amdgcn_update_dpp(
        0, __float_as_int(v), 0x128, 0xF, 0xF, true));
}
__device__ __forceinline__ float xor16p(float v, bool hi) {
#ifdef HAVE_PL16
    v2u r = __builtin_amdgcn_permlane16_swap(
        (unsigned)__float_as_int(v), (unsigned)__float_as_int(v), false, false);
    return __int_as_float((int)(hi ? r.x : r.y));
#else
    return __shfl_xor(v, 16);
#endif
}
__device__ __forceinline__ float xor32p(float v, bool hi) {
#ifdef HAVE_PL32
    v2u r = __builtin_amdgcn_permlane32_swap(
        (unsigned)__float_as_int(v), (unsigned)__float_as_int(v), false, false);
    return __int_as_float((int)(hi ? r.x : r.y));
#else
    return __shfl_xor(v, 32);
#endif
}

template<int Q>
__device__ __forceinline__ float lane_xor(float v, bool hi) {
    if constexpr (Q == 0) return xor1p(v);
    else if constexpr (Q == 1) return xor2p(v);
    else if constexpr (Q == 2) return xor4p(v);
    else if constexpr (Q == 3) return xor8p(v);
    else if constexpr (Q == 4) return xor16p(v, hi);
    else return xor32p(v, hi);
}

// ---- packed complex gate core (verified r5/r6, absmax 0) ----
// cgate<false>(v,w) = A v + B w           (row select-bit = 0)
// cgate<true >(v,w) = conj(A) v - conj(B) w  (row select-bit = 1)
template<bool NEG>
__device__ __forceinline__ float2 cgate(const float2 ar2, const float2 ai2,
                                        const float2 br2, const float2 bi2,
                                        const float2 v, const float2 w) {
    float2 acc;
    asm("v_pk_mul_f32 %0, %1, %2" : "=v"(acc) : "v"(ar2), "v"(v));
    if constexpr (!NEG) {
        asm("v_pk_fma_f32 %0, %1, %2, %0 op_sel:[0,1,0] op_sel_hi:[1,0,1] neg_lo:[0,1,0]"
            : "+v"(acc) : "v"(ai2), "v"(v));
        asm("v_pk_fma_f32 %0, %1, %2, %0" : "+v"(acc) : "v"(br2), "v"(w));
    } else {
        asm("v_pk_fma_f32 %0, %1, %2, %0 op_sel:[0,1,0] op_sel_hi:[1,0,1] neg_lo:[1,1,0] neg_hi:[1,0,0]"
            : "+v"(acc) : "v"(ai2), "v"(v));
        asm("v_pk_fma_f32 %0, %1, %2, %0 neg_lo:[1,0,0] neg_hi:[1,0,0]"
            : "+v"(acc) : "v"(br2), "v"(w));
    }
    asm("v_pk_fma_f32 %0, %1, %2, %0 op_sel:[0,1,0] op_sel_hi:[1,0,1] neg_lo:[0,1,0]"
        : "+v"(acc) : "v"(bi2), "v"(w));
    return acc;
}

template<int Q>
__device__ __forceinline__ void lane_gate(float2 (&st)[8], int lane,
                                          float ar, float ai, float br, float bi) {
    const bool hi = (lane & (1 << Q)) != 0;
    const float aiL = hi ? -ai : ai;
    const float brL = hi ? -br : br;
    const float2 ar2 = make_float2(ar, ar);
    const float2 ai2 = make_float2(aiL, aiL);
    const float2 br2 = make_float2(brL, brL);
    const float2 bi2 = make_float2(bi, bi);
    #pragma unroll
    for (int r = 0; r < 8; ++r) {
        float2 p;
        p.x = lane_xor<Q>(st[r].x, hi);
        p.y = lane_xor<Q>(st[r].y, hi);
        st[r] = cgate<false>(ar2, ai2, br2, bi2, st[r], p);
    }
}

template<int RB>
__device__ __forceinline__ void reg_gate(float2 (&st)[8],
                                         float ar, float ai, float br, float bi) {
    const float2 ar2 = make_float2(ar, ar);
    const float2 ai2 = make_float2(ai, ai);
    const float2 br2 = make_float2(br, br);
    const float2 bi2 = make_float2(bi, bi);
    #pragma unroll
    for (int r = 0; r < 8; ++r) {
        if ((r & RB) == 0) {
            const int r1 = r | RB;
            const float2 v0 = st[r], v1 = st[r1];
            st[r]  = cgate<false>(ar2, ai2, br2, bi2, v0, v1);
            st[r1] = cgate<true >(ar2, ai2, br2, bi2, v1, v0);
        }
    }
}

__global__ __launch_bounds__(128, 4) void cqv_kernel(
    const float* __restrict__ x,
    const float* __restrict__ theta,
    const float* __restrict__ alpha_raw,
    const float* __restrict__ beta_raw,
    const float* __restrict__ head_w,
    const float* __restrict__ head_b,
    const float* __restrict__ logit_scale,
    float* __restrict__ out,
    int batch)
{
    const int lane = threadIdx.x & 63;
    const int wv = threadIdx.x >> 6;           // qubit-9 bit of this wave
    const int s = blockIdx.x;                  // one sample per block (grid exact)

    // [buf][reg][wv][lane] ; + epilogue partials. 8KB + 8B.
    __shared__ float2 lds[2][8][2][64];
    __shared__ float pbuf[2];

    const int l5 = (lane >> 5) & 1;
    const int srcLane = lane ^ ((lane & 31) << 1);

    // ---- per-lane gate params: lane g holds gate g = layer*10 + qubit ----
    const int g = (lane < 30) ? lane : 0;
    const float alpha = log1pf(__expf(alpha_raw[g])) + 1e-6f;
    const float beta  = tanhf(beta_raw[g]);
    const float halfE = 0.5f * PI_F * (alpha * x[s * 49 + g] + beta);
    float cE, sE, cT, sT;
    __sincosf(halfE, &sE, &cE);
    __sincosf(0.5f * theta[g], &sT, &cT);

    float2 st[8];

    // ---- layer 0 on |0..0>: product state, q9 factor chosen by wv ----
    {
        float u0r[10], u0i[10], u1r[10], u1i[10];
        #pragma unroll
        for (int q = 0; q < 10; ++q) {
            const float ce = rdlane(cE, q), se = rdlane(sE, q);
            const float ct = rdlane(cT, q), s_t = rdlane(sT, q);
            u0r[q] = ct * ce;  u0i[q] = -s_t * se;   // A
            u1r[q] = ct * se;  u1i[q] = -s_t * ce;   // -conj(B)
        }
        float plr = 1.f, pli = 0.f;                  // lane bits 0..5
        #pragma unroll
        for (int q = 0; q < 6; ++q) {
            const bool bq = (lane >> q) & 1;
            const float wr = bq ? u1r[q] : u0r[q];
            const float wi = bq ? u1i[q] : u0i[q];
            const float nr = plr * wr - pli * wi;
            const float ni = plr * wi + pli * wr;
            plr = nr; pli = ni;
        }
        const float w9r = wv ? u1r[9] : u0r[9], w9i = wv ? u1i[9] : u0i[9];
        float t67r[4], t67i[4], t89r[2], t89i[2];
        #pragma unroll
        for (int a = 0; a < 4; ++a) {
            const float w6r = (a & 1) ? u1r[6] : u0r[6], w6i = (a & 1) ? u1i[6] : u0i[6];
            const float w7r = (a & 2) ? u1r[7] : u0r[7], w7i = (a & 2) ? u1i[7] : u0i[7];
            t67r[a] = w6r * w7r - w6i * w7i;  t67i[a] = w6r * w7i + w6i * w7r;
        }
        #pragma unroll
        for (int k = 0; k < 2; ++k) {
            const float w8r = k ? u1r[8] : u0r[8], w8i = k ? u1i[8] : u0i[8];
            t89r[k] = w8r * w9r - w8i * w9i;  t89i[k] = w8r * w9i + w8i * w9r;
        }
        #pragma unroll
        for (int r = 0; r < 8; ++r) {
            const float ar = t67r[r & 3] * t89r[r >> 2] - t67i[r & 3] * t89i[r >> 2];
            const float ai = t67r[r & 3] * t89i[r >> 2] + t67i[r & 3] * t89r[r >> 2];
            st[r].x = ar * plr - ai * pli;
            st[r].y = ar * pli + ai * plr;
        }
    }

    // ---- layer-0 CNOT chain: pure cross-wave permutation (buf 0) ----
    {
        #pragma unroll
        for (int r = 0; r < 8; ++r) lds[0][r][wv][lane] = st[r];
        __syncthreads();
        #pragma unroll
        for (int r = 0; r < 8; ++r) {
            const int sReg = (r ^ ((r & 3) << 1)) ^ l5;
            const int k9 = wv ^ (r >> 2);
            st[r] = lds[0][sReg][k9][srcLane];
        }
    }

#define GATE_PARAMS(BASE, Q) \
        const float ce = rdlane(cE, (BASE) + (Q)), se = rdlane(sE, (BASE) + (Q)); \
        const float ct = rdlane(cT, (BASE) + (Q)), s_t = rdlane(sT, (BASE) + (Q));
#define APPLY_LANE_GATE(BASE, Q) { GATE_PARAMS(BASE, Q) \
        lane_gate<Q>(st, lane, ct * ce, -s_t * se, -ct * se, -s_t * ce); }
#define APPLY_REG_GATE(BASE, Q, RB) { GATE_PARAMS(BASE, Q) \
        reg_gate<RB>(st, ct * ce, -s_t * se, -ct * se, -s_t * ce); }
#define APPLY_Q0_Q8(BASE) \
        APPLY_LANE_GATE(BASE, 0) APPLY_LANE_GATE(BASE, 1) APPLY_LANE_GATE(BASE, 2) \
        APPLY_LANE_GATE(BASE, 3) APPLY_LANE_GATE(BASE, 4) APPLY_LANE_GATE(BASE, 5) \
        APPLY_REG_GATE(BASE, 6, 1) APPLY_REG_GATE(BASE, 7, 2) APPLY_REG_GATE(BASE, 8, 4)

    // ---- layer 1: q0..q8 in-wave; q9 fused into CNOT exchange (buf 1) ----
    {
        APPLY_Q0_Q8(10)
        GATE_PARAMS(10, 9)
        const float ar = ct * ce, ai = -s_t * se, br = -ct * se, bi = -s_t * ce;
        const float2 ar2 = make_float2(ar, ar), ai2 = make_float2(ai, ai);
        const float2 br2 = make_float2(br, br), bi2 = make_float2(bi, bi);
        #pragma unroll
        for (int r = 0; r < 8; ++r) lds[1][r][wv][lane] = st[r];
        __syncthreads();
        #pragma unroll
        for (int r = 0; r < 8; ++r) {
            const int sReg = (r ^ ((r & 3) << 1)) ^ l5;
            const int k9 = wv ^ (r >> 2);
            const float2 v = lds[1][sReg][k9][srcLane];
            const float2 w = lds[1][sReg][k9 ^ 1][srcLane];
            if (k9 == 0) st[r] = cgate<false>(ar2, ai2, br2, bi2, v, w);
            else         st[r] = cgate<true >(ar2, ai2, br2, bi2, v, w);
        }
    }

    // ---- layer 2: q0..q8 in-wave; q9 = same-address pair swap (buf 0,
    // safe: L1's barrier orders all L0 reads before this write). The final
    // CNOT chain is absorbed into the head weights below. ----
    {
        APPLY_Q0_Q8(20)
        GATE_PARAMS(20, 9)
        const float ar = ct * ce, ai = -s_t * se, br = -ct * se, bi = -s_t * ce;
        const float2 ar2 = make_float2(ar, ar), ai2 = make_float2(ai, ai);
        const float2 br2 = make_float2(br, br), bi2 = make_float2(bi, bi);
        #pragma unroll
        for (int r = 0; r < 8; ++r) lds[0][r][wv][lane] = st[r];
        __syncthreads();
        #pragma unroll
        for (int r = 0; r < 8; ++r) {
            const float2 w = lds[0][r][wv ^ 1][lane];   // partner amplitude
            if (wv == 0) st[r] = cgate<false>(ar2, ai2, br2, bi2, st[r], w);
            else         st[r] = cgate<true >(ar2, ai2, br2, bi2, st[r], w);
        }
    }
#undef GATE_PARAMS
#undef APPLY_LANE_GATE
#undef APPLY_REG_GATE
#undef APPLY_Q0_Q8

    // ---- epilogue with permuted weights W'(k) = sum_q w_q*(1-2*prefix_q(k)),
    // prefix_q(k) = k_0^..^k_q  (absorbs the final CNOT chain). ----
    float w[10];
    #pragma unroll
    for (int q = 0; q < 10; ++q) w[q] = head_w[q];
    // lane part: prefixes of bits 0..5, and lane parity sign
    float wlane = 0.f;
    {
        int pref = 0;
        #pragma unroll
        for (int q = 0; q < 6; ++q) {
            pref ^= (lane >> q) & 1;
            wlane += pref ? -w[q] : w[q];
        }
    }
    const float sPL = ((__builtin_popcount(lane & 63) & 1) ? -1.f : 1.f);
    // reg+wv part: wreg'(r) = w6*s(r0) + w7*s(r0^r1) + w8*s(pr2) + w9*s(pr2^wv)
    float acc = 0.f, psum = 0.f;
    #pragma unroll
    for (int r = 0; r < 8; ++r) {
        const float pw = st[r].x * st[r].x + st[r].y * st[r].y;
        const int p0 = r & 1, p1 = p0 ^ ((r >> 1) & 1), p2 = p1 ^ ((r >> 2) & 1);
        const float wr = (p0 ? -w[6] : w[6]) + (p1 ? -w[7] : w[7])
                       + (p2 ? -w[8] : w[8]) + ((p2 ^ wv) ? -w[9] : w[9]);
        psum += pw;
        acc = fmaf(wr, pw, acc);
    }
    float partial = fmaf(wlane, psum, sPL * acc);
    #pragma unroll
    for (int off = 32; off >= 1; off >>= 1) partial += __shfl_xor(partial, off);

    if (lane == 0) pbuf[wv] = partial;
    __syncthreads();
    if (threadIdx.x == 0) {
        const float scale = fminf(fmaxf(logit_scale[0], 0.5f), 80.f);
        const float raw = pbuf[0] + pbuf[1] + head_b[0];
        out[s] = fminf(fmaxf(scale * raw, -30.f), 30.f);
    }
}

extern "C" void kernel_launch(void* const* d_in, const int* in_sizes, int n_in,
                              void* d_out, int out_size, void* d_ws, size_t ws_size,
                              hipStream_t stream) {
    const int B = in_sizes[0] / 49;          // BATCH = 2048
    dim3 block(128);                         // 2 waves = 1 sample
    dim3 grid(B);
    cqv_kernel<<<grid, block, 0, stream>>>(
        (const float*)d_in[0], (const float*)d_in[1], (const float*)d_in[2],
        (const float*)d_in[3], (const float*)d_in[4], (const float*)d_in[5],
        (const float*)d_in[6], (float*)d_out, B);
}